// Round 1
// baseline (1050.446 us; speedup 1.0000x reference)
//
#include <hip/hip_runtime.h>
#include <math.h>

#define FIBER   128
#define HIDDEN  1024
#define IN_DIM  1152
#define OUT_DIMM 512
#define EPS_C   1e-4f
#define BM      32
#define PADX    1160   // IN_DIM + 8 (ushorts)
#define PADH    1032   // HIDDEN + 8 (ushorts)
#define PADY    520    // OUT_DIMM + 8 (floats)

typedef __attribute__((ext_vector_type(8))) __bf16 bf16x8;
typedef __attribute__((ext_vector_type(4))) float  f32x4;

#define MFMA16(a, b, c) __builtin_amdgcn_mfma_f32_16x16x32_bf16(a, b, c, 0, 0, 0)

static __device__ __forceinline__ unsigned short f2bf(float f) {
    union { float f; unsigned u; } v; v.f = f;
    unsigned r = v.u + 0x7fffu + ((v.u >> 16) & 1u);
    return (unsigned short)(r >> 16);
}

static __device__ __forceinline__ uint4 pack8(const float* v) {
    uint4 p;
    p.x = (unsigned)f2bf(v[0]) | ((unsigned)f2bf(v[1]) << 16);
    p.y = (unsigned)f2bf(v[2]) | ((unsigned)f2bf(v[3]) << 16);
    p.z = (unsigned)f2bf(v[4]) | ((unsigned)f2bf(v[5]) << 16);
    p.w = (unsigned)f2bf(v[6]) | ((unsigned)f2bf(v[7]) << 16);
    return p;
}

// Pack W [K x Ndim] f32 row-major -> bf16 MFMA B-fragments.
// Fragment (kt, nt): lane holds B[kt*32 + 8*(lane>>4) + i][nt*16 + (lane&15)], i=0..7.
// Stored at frag*512 + lane*8 ushorts (one dwordx4 per lane, coalesced).
__global__ void pack_w_kernel(const float* __restrict__ W, unsigned short* __restrict__ outp,
                              int Ndim, int ntShift, int totFrag) {
    int tid  = blockIdx.x * 256 + threadIdx.x;
    int frag = tid >> 6;
    if (frag >= totFrag) return;
    int lane = tid & 63;
    int nt = frag & ((1 << ntShift) - 1);
    int kt = frag >> ntShift;
    int k0 = kt * 32 + ((lane >> 4) << 3);
    int n  = nt * 16 + (lane & 15);
    float v[8];
#pragma unroll
    for (int i = 0; i < 8; ++i) v[i] = W[(size_t)(k0 + i) * Ndim + n];
    *reinterpret_cast<uint4*>(outp + (size_t)frag * 512 + lane * 8) = pack8(v);
}

__global__ __launch_bounds__(512)
void fused_mlp_kernel(const float* __restrict__ x,
                      const float* __restrict__ rot,
                      const float* __restrict__ extra,
                      const float* __restrict__ b1,
                      const float* __restrict__ b2,
                      const bf16x8* __restrict__ w1p,
                      const bf16x8* __restrict__ w2p,
                      float* __restrict__ out,
                      int nrows) {
    __shared__ __align__(16) unsigned short x1s[BM * PADX]; // 74240 B (reused as ys f32 later)
    __shared__ __align__(16) unsigned short hs[BM * PADH];  // 66048 B
    __shared__ float R_s[BM][9];

    const int tid  = threadIdx.x;
    const int row0 = blockIdx.x * BM;

    // ---------- phase 1: build x1 (bf16) into LDS ----------
    {
        const int m   = tid >> 4;   // row 0..31
        const int l16 = tid & 15;
        const int i   = row0 + m;
        unsigned short* xr = x1s + m * PADX;
        if (i < nrows) {
            float r[9];
#pragma unroll
            for (int q = 0; q < 9; ++q) r[q] = rot[(size_t)i * 9 + q];
            if (l16 < 9) R_s[m][l16] = r[l16];
            const float* xp = x + (size_t)i * 512;
            const int f0 = l16 * 8;
            float xv[4][8];
#pragma unroll
            for (int c = 0; c < 4; ++c) {
                float4 lo = *reinterpret_cast<const float4*>(xp + c * 128 + f0);
                float4 hi = *reinterpret_cast<const float4*>(xp + c * 128 + f0 + 4);
                xv[c][0] = lo.x; xv[c][1] = lo.y; xv[c][2] = lo.z; xv[c][3] = lo.w;
                xv[c][4] = hi.x; xv[c][5] = hi.y; xv[c][6] = hi.z; xv[c][7] = hi.w;
            }
            // x[:,0] passthrough -> [0,128)
            *reinterpret_cast<uint4*>(xr + f0) = pack8(xv[0]);
            // vec_local -> [128,512), vec_norm -> [512,640)
            float nv[8];
#pragma unroll
            for (int j = 0; j < 8; ++j) {
                const int f = f0 + j;
                const float a = xv[1][j], b = xv[2][j], c = xv[3][j];
#pragma unroll
                for (int k = 0; k < 3; ++k)
                    xr[FIBER + 3 * f + k] = f2bf(a * r[k] + b * r[3 + k] + c * r[6 + k]);
                nv[j] = sqrtf(a * a + b * b + c * c + EPS_C);
            }
            *reinterpret_cast<uint4*>(xr + 512 + f0) = pack8(nv);
            // extra -> [640,1152)
            const float* ep = extra + (size_t)i * 512 + l16 * 32;
#pragma unroll
            for (int q = 0; q < 4; ++q) {
                float ev[8];
                float4 lo = *reinterpret_cast<const float4*>(ep + q * 8);
                float4 hi = *reinterpret_cast<const float4*>(ep + q * 8 + 4);
                ev[0]=lo.x; ev[1]=lo.y; ev[2]=lo.z; ev[3]=lo.w;
                ev[4]=hi.x; ev[5]=hi.y; ev[6]=hi.z; ev[7]=hi.w;
                *reinterpret_cast<uint4*>(xr + 640 + l16 * 32 + q * 8) = pack8(ev);
            }
        } else {
            if (l16 < 9) R_s[m][l16] = 0.0f;
            const uint4 z = {0u, 0u, 0u, 0u};
            for (int ch = l16; ch < IN_DIM / 8; ch += 16)
                *reinterpret_cast<uint4*>(xr + ch * 8) = z;
        }
    }
    __syncthreads();

    const int w    = tid >> 6;   // wave 0..7
    const int lane = tid & 63;
    const int lr   = lane & 15;  // A-row / B-col / C-col
    const int lk   = lane >> 4;  // k-group / C-row-group

    // ---------- phase 2: GEMM1  h = gelu(x1 @ W1 + b1) ----------
    // wave w owns N-cols [w*128, w*128+128): nt = w*8 + nti
    f32x4 acc1[2][8];
#pragma unroll
    for (int mt = 0; mt < 2; ++mt)
#pragma unroll
        for (int q = 0; q < 8; ++q) acc1[mt][q] = (f32x4){0.f, 0.f, 0.f, 0.f};

    for (int kt = 0; kt < 36; ++kt) {
        const bf16x8 a0 = *reinterpret_cast<const bf16x8*>(x1s + lr * PADX + kt * 32 + lk * 8);
        const bf16x8 a1 = *reinterpret_cast<const bf16x8*>(x1s + (lr + 16) * PADX + kt * 32 + lk * 8);
        const bf16x8* wk = w1p + ((size_t)(kt * 64 + w * 8)) * 64 + lane;
#pragma unroll
        for (int nti = 0; nti < 8; ++nti) {
            const bf16x8 bfr = wk[(size_t)nti * 64];
            acc1[0][nti] = MFMA16(a0, bfr, acc1[0][nti]);
            acc1[1][nti] = MFMA16(a1, bfr, acc1[1][nti]);
        }
    }
    // bias + exact GELU -> hs (bf16, row-major [32][PADH])
#pragma unroll
    for (int nti = 0; nti < 8; ++nti) {
        const int col = w * 128 + nti * 16 + lr;
        const float bv = b1[col];
#pragma unroll
        for (int mt = 0; mt < 2; ++mt) {
#pragma unroll
            for (int j = 0; j < 4; ++j) {
                const float v = acc1[mt][nti][j] + bv;
                const float g = 0.5f * v * (1.0f + erff(v * 0.70710678118654752f));
                hs[(mt * 16 + lk * 4 + j) * PADH + col] = f2bf(g);
            }
        }
    }
    __syncthreads();

    // ---------- phase 3: GEMM2  y = h @ W2 + b2 ----------
    // wave w owns N-cols [w*64, w*64+64): nt = w*4 + nti
    f32x4 acc2[2][4];
#pragma unroll
    for (int mt = 0; mt < 2; ++mt)
#pragma unroll
        for (int q = 0; q < 4; ++q) acc2[mt][q] = (f32x4){0.f, 0.f, 0.f, 0.f};

    for (int kt = 0; kt < 32; ++kt) {
        const bf16x8 a0 = *reinterpret_cast<const bf16x8*>(hs + lr * PADH + kt * 32 + lk * 8);
        const bf16x8 a1 = *reinterpret_cast<const bf16x8*>(hs + (lr + 16) * PADH + kt * 32 + lk * 8);
        const bf16x8* wk = w2p + ((size_t)(kt * 32 + w * 4)) * 64 + lane;
#pragma unroll
        for (int nti = 0; nti < 4; ++nti) {
            const bf16x8 bfr = wk[(size_t)nti * 64];
            acc2[0][nti] = MFMA16(a0, bfr, acc2[0][nti]);
            acc2[1][nti] = MFMA16(a1, bfr, acc2[1][nti]);
        }
    }
    // stage y (f32) into LDS, aliasing x1s (all x1 reads finished at previous barrier)
    float* ys = reinterpret_cast<float*>(x1s);
#pragma unroll
    for (int nti = 0; nti < 4; ++nti) {
        const int col = w * 64 + nti * 16 + lr;
        const float bv = b2[col];
#pragma unroll
        for (int mt = 0; mt < 2; ++mt)
#pragma unroll
            for (int j = 0; j < 4; ++j)
                ys[(mt * 16 + lk * 4 + j) * PADY + col] = acc2[mt][nti][j] + bv;
    }
    __syncthreads();

    // ---------- phase 4: epilogue rotation + store ----------
    {
        const int n = tid;          // output column 0..511
        const int p = n >> 7;
        const int f = n & 127;
        float* op = out + (size_t)row0 * 512 + n;
        if (p == 0) {
#pragma unroll 4
            for (int m = 0; m < BM; ++m) {
                if (row0 + m < nrows) op[(size_t)m * 512] = ys[m * PADY + f];
            }
        } else {
            const int c = p - 1;
#pragma unroll 4
            for (int m = 0; m < BM; ++m) {
                if (row0 + m < nrows) {
                    const float v = R_s[m][c * 3 + 0] * ys[m * PADY + 128 + f]
                                  + R_s[m][c * 3 + 1] * ys[m * PADY + 256 + f]
                                  + R_s[m][c * 3 + 2] * ys[m * PADY + 384 + f];
                    op[(size_t)m * 512] = v;
                }
            }
        }
    }
}

extern "C" void kernel_launch(void* const* d_in, const int* in_sizes, int n_in,
                              void* d_out, int out_size, void* d_ws, size_t ws_size,
                              hipStream_t stream) {
    const float* x     = (const float*)d_in[0];
    const float* rot   = (const float*)d_in[1];
    const float* extra = (const float*)d_in[2];
    const float* W1    = (const float*)d_in[3];
    const float* b1    = (const float*)d_in[4];
    const float* W2    = (const float*)d_in[5];
    const float* b2    = (const float*)d_in[6];
    float* out = (float*)d_out;

    const int nrows = in_sizes[0] / 512;

    // ws layout: W1 packed (36*64 frags * 1024 B = 2,359,296 B) | W2 packed (1024 frags = 1,048,576 B)
    unsigned short* w1p = (unsigned short*)d_ws;
    unsigned short* w2p = (unsigned short*)((char*)d_ws + (size_t)36 * 64 * 1024);

    pack_w_kernel<<<(36 * 64 * 64 + 255) / 256, 256, 0, stream>>>(W1, w1p, HIDDEN, 6, 36 * 64);
    pack_w_kernel<<<(32 * 32 * 64 + 255) / 256, 256, 0, stream>>>(W2, w2p, OUT_DIMM, 5, 32 * 32);

    const int nblk = (nrows + BM - 1) / BM;
    fused_mlp_kernel<<<nblk, 512, 0, stream>>>(x, rot, extra, b1, b2,
                                               (const bf16x8*)w1p, (const bf16x8*)w2p,
                                               out, nrows);
}

// Round 2
// 567.245 us; speedup vs baseline: 1.8518x; 1.8518x over previous
//
#include <hip/hip_runtime.h>
#include <math.h>

#define HIDDEN   1024
#define IN_DIM   1152
#define OUT_D    512
#define EPS_C    1e-4f
#define BMA      64
#define HBLK_BYTES 131072   // 64 rows * 1024 cols * 2 B (frag-major h block)

typedef __attribute__((ext_vector_type(8))) __bf16 bf16x8;
typedef __attribute__((ext_vector_type(4))) float  f32x4;

#define MFMA16(a, b, c) __builtin_amdgcn_mfma_f32_16x16x32_bf16(a, b, c, 0, 0, 0)

static __device__ __forceinline__ unsigned short f2bf(float f) {
    union { float f; unsigned u; } v; v.f = f;
    unsigned r = v.u + 0x7fffu + ((v.u >> 16) & 1u);
    return (unsigned short)(r >> 16);
}

static __device__ __forceinline__ uint4 pack8(const float* v) {
    uint4 p;
    p.x = (unsigned)f2bf(v[0]) | ((unsigned)f2bf(v[1]) << 16);
    p.y = (unsigned)f2bf(v[2]) | ((unsigned)f2bf(v[3]) << 16);
    p.z = (unsigned)f2bf(v[4]) | ((unsigned)f2bf(v[5]) << 16);
    p.w = (unsigned)f2bf(v[6]) | ((unsigned)f2bf(v[7]) << 16);
    return p;
}

// tanh-form GELU via sigmoid: g = v * sigmoid(c1*v + c3*v^3), max err ~1e-3
static __device__ __forceinline__ float gelu_f(float v) {
    const float t = -v * (1.5957691216f + 0.0713548163f * v * v);
    return v / (1.0f + __expf(t));
}

// Pack W [K x Ndim] f32 row-major -> bf16 MFMA B-fragments.
// Fragment (kt, nt): lane holds B[kt*32 + 8*(lane>>4) + i][nt*16 + (lane&15)], i=0..7.
// Stored at frag*512 + lane*8 ushorts.
__global__ void pack_w_kernel(const float* __restrict__ W, unsigned short* __restrict__ outp,
                              int Ndim, int ntShift, int totFrag) {
    int tid  = blockIdx.x * 256 + threadIdx.x;
    int frag = tid >> 6;
    if (frag >= totFrag) return;
    int lane = tid & 63;
    int nt = frag & ((1 << ntShift) - 1);
    int kt = frag >> ntShift;
    int k0 = kt * 32 + ((lane >> 4) << 3);
    int n  = nt * 16 + (lane & 15);
    float v[8];
#pragma unroll
    for (int i = 0; i < 8; ++i) v[i] = W[(size_t)(k0 + i) * Ndim + n];
    *reinterpret_cast<uint4*>(outp + (size_t)frag * 512 + lane * 8) = pack8(v);
}

// ================= Kernel A: features + GEMM1 + GELU -> h (frag-major, global) ==========
__global__ __launch_bounds__(512, 2)
void gemm1_kernel(const float* __restrict__ x, const float* __restrict__ rot,
                  const float* __restrict__ extra, const float* __restrict__ b1,
                  const bf16x8* __restrict__ w1p,
                  char* __restrict__ hmain, char* __restrict__ hspill,
                  int nrows, int spill_start) {
    // x1 in A-fragment-major layout: frag (kt,mt) at (kt*4+mt)*1024 B, lane-linear 16B
    __shared__ __align__(16) unsigned short x1f[36 * 4 * 512];   // 147456 B

    const int tid  = threadIdx.x;
    const int bid  = blockIdx.x;
    const int row0 = bid * BMA;

    // ---------------- phase 1: build x1 (bf16) in frag-major LDS ----------------
#pragma unroll
    for (int hh = 0; hh < 2; ++hh) {
        const int m   = (tid >> 4) + hh * 32;
        const int l16 = tid & 15;
        const int i   = row0 + m;
        const int mt  = m >> 4;
        const int lr8 = (m & 15) * 8;
        const bool valid = (i < nrows);
        const int f0 = l16 * 8;

        float r[9];
#pragma unroll
        for (int q = 0; q < 9; ++q) r[q] = 0.0f;
        float xv[4][8];
#pragma unroll
        for (int c = 0; c < 4; ++c)
#pragma unroll
            for (int q = 0; q < 8; ++q) xv[c][q] = 0.0f;

        if (valid) {
#pragma unroll
            for (int q = 0; q < 9; ++q) r[q] = rot[(size_t)i * 9 + q];
            const float* xp = x + (size_t)i * 512;
#pragma unroll
            for (int c = 0; c < 4; ++c) {
                float4 lo = *reinterpret_cast<const float4*>(xp + c * 128 + f0);
                float4 hi = *reinterpret_cast<const float4*>(xp + c * 128 + f0 + 4);
                xv[c][0]=lo.x; xv[c][1]=lo.y; xv[c][2]=lo.z; xv[c][3]=lo.w;
                xv[c][4]=hi.x; xv[c][5]=hi.y; xv[c][6]=hi.z; xv[c][7]=hi.w;
            }
        }
        // x[:,0] -> k [0,128)
        {
            const int base0 = ((l16 >> 2) * 4 + mt) * 512 + (l16 & 3) * 128 + lr8;
            *reinterpret_cast<uint4*>(x1f + base0) = pack8(xv[0]);
        }
        // vec_local -> k [128,512) (scalar scatter), vec_norm -> k [512,640)
        float nv[8];
#pragma unroll
        for (int j = 0; j < 8; ++j) {
            const float a = xv[1][j], b = xv[2][j], c = xv[3][j];
            const int kb = 128 + 3 * (f0 + j);
#pragma unroll
            for (int kk = 0; kk < 3; ++kk) {
                const float vl = a * r[kk] + b * r[3 + kk] + c * r[6 + kk];
                const int k = kb + kk;
                x1f[((k >> 5) * 4 + mt) * 512 + ((k >> 3) & 3) * 128 + lr8 + (k & 7)] = f2bf(vl);
            }
            nv[j] = sqrtf(a * a + b * b + c * c + EPS_C);
        }
        {
            const int basen = ((16 + (l16 >> 2)) * 4 + mt) * 512 + (l16 & 3) * 128 + lr8;
            *reinterpret_cast<uint4*>(x1f + basen) = pack8(nv);
        }
        // extra -> k [640,1152)
        const float* ep = extra + (size_t)i * 512 + l16 * 32;
#pragma unroll
        for (int q = 0; q < 4; ++q) {
            float ev[8];
#pragma unroll
            for (int z = 0; z < 8; ++z) ev[z] = 0.0f;
            if (valid) {
                float4 lo = *reinterpret_cast<const float4*>(ep + q * 8);
                float4 hi = *reinterpret_cast<const float4*>(ep + q * 8 + 4);
                ev[0]=lo.x; ev[1]=lo.y; ev[2]=lo.z; ev[3]=lo.w;
                ev[4]=hi.x; ev[5]=hi.y; ev[6]=hi.z; ev[7]=hi.w;
            }
            const int basee = ((20 + l16) * 4 + mt) * 512 + q * 128 + lr8;
            *reinterpret_cast<uint4*>(x1f + basee) = pack8(ev);
        }
    }
    __syncthreads();

    // ---------------- phase 2: GEMM1, double-buffered weight prefetch ----------------
    const int w    = tid >> 6;
    const int lane = tid & 63;
    const int lr   = lane & 15;
    const int lk   = lane >> 4;

    f32x4 acc[4][8];
#pragma unroll
    for (int mt = 0; mt < 4; ++mt)
#pragma unroll
        for (int n = 0; n < 8; ++n) acc[mt][n] = (f32x4){0.f, 0.f, 0.f, 0.f};

    const bf16x8* wb = w1p + (size_t)w * 512 + lane;

    auto LB1 = [&](bf16x8* B, int kt) {
#pragma unroll
        for (int n = 0; n < 8; ++n) B[n] = wb[(size_t)kt * 4096 + n * 64];
    };
    auto MM1 = [&](const bf16x8* B, int kt) {
        const unsigned short* ab = x1f + kt * 2048 + lane * 8;
#pragma unroll
        for (int mt = 0; mt < 4; ++mt) {
            const bf16x8 a = *reinterpret_cast<const bf16x8*>(ab + mt * 512);
#pragma unroll
            for (int n = 0; n < 8; ++n) acc[mt][n] = MFMA16(a, B[n], acc[mt][n]);
        }
    };

    bf16x8 B0[8], B1[8];
    LB1(B0, 0);
    for (int kt = 0; kt < 34; kt += 2) {
        LB1(B1, kt + 1);
        MM1(B0, kt);
        LB1(B0, kt + 2);
        MM1(B1, kt + 1);
    }
    LB1(B1, 35);
    MM1(B0, 34);
    MM1(B1, 35);

    __syncthreads();   // all x1f reads done; reuse as h frag buffer

    // ---------------- phase 3: bias + GELU -> h frag-major in LDS, then coalesced store ----------------
    unsigned short* hf = x1f;
    float bv[8];
#pragma unroll
    for (int n = 0; n < 8; ++n) bv[n] = b1[w * 128 + n * 16 + lr];
#pragma unroll
    for (int n = 0; n < 8; ++n) {
        const int ktn = w * 4 + (n >> 1);
        const int sub = ((n & 1) * 2 + (lr >> 3)) * 128 + (lr & 7);
#pragma unroll
        for (int mt = 0; mt < 4; ++mt) {
#pragma unroll
            for (int j = 0; j < 4; ++j) {
                const float v = acc[mt][n][j] + bv[n];
                hf[(ktn * 4 + mt) * 512 + sub + (lk * 4 + j) * 8] = f2bf(gelu_f(v));
            }
        }
    }
    __syncthreads();

    char* hdst = (bid < spill_start) ? (hmain + (size_t)bid * HBLK_BYTES)
                                     : (hspill + (size_t)(bid - spill_start) * HBLK_BYTES);
    const uint4* s4 = reinterpret_cast<const uint4*>(hf);
    uint4* d4 = reinterpret_cast<uint4*>(hdst);
#pragma unroll
    for (int c = 0; c < 16; ++c) d4[tid + c * 512] = s4[tid + c * 512];
}

// ================= Kernel B: GEMM2 + bias + rotation epilogue ==========
__global__ __launch_bounds__(512, 2)
void gemm2_kernel(const float* __restrict__ rot, const float* __restrict__ b2,
                  const bf16x8* __restrict__ w2p,
                  const char* __restrict__ hmain, const char* __restrict__ hspill,
                  float* __restrict__ out, int nrows, int spill_start) {
    __shared__ __align__(16) unsigned short hf[32 * 4 * 512];   // 131072 B (reused as ys f32)
    __shared__ float R_s[BMA * 9];

    const int tid  = threadIdx.x;
    const int bid  = blockIdx.x;
    const int row0 = bid * BMA;
    const int lane = tid & 63;
    const int w    = tid >> 6;

    const char* hsrc = (bid < spill_start) ? (hmain + (size_t)bid * HBLK_BYTES)
                                           : (hspill + (size_t)(bid - spill_start) * HBLK_BYTES);

    // stage h: global -> LDS direct (wave-uniform dest + lane*16), 128 chunks of 1 KB
#pragma unroll
    for (int c = 0; c < 16; ++c) {
        const int chunk = w * 16 + c;
        __builtin_amdgcn_global_load_lds(
            (const __attribute__((address_space(1))) unsigned int*)(hsrc + chunk * 1024 + lane * 16),
            (__attribute__((address_space(3))) unsigned int*)(&hf[chunk * 512]),
            16, 0, 0);
    }
    for (int t = tid; t < BMA * 9; t += 512) {
        const int idx = row0 * 9 + t;
        R_s[t] = (idx < nrows * 9) ? rot[idx] : 0.0f;
    }
    __syncthreads();

    // ---------------- GEMM2, triple-buffered weight prefetch ----------------
    const int lr = lane & 15;
    const int lk = lane >> 4;

    f32x4 acc[4][4];
#pragma unroll
    for (int mt = 0; mt < 4; ++mt)
#pragma unroll
        for (int n = 0; n < 4; ++n) acc[mt][n] = (f32x4){0.f, 0.f, 0.f, 0.f};

    const bf16x8* wb = w2p + (size_t)w * 256 + lane;

    auto LB2 = [&](bf16x8* B, int kt) {
#pragma unroll
        for (int n = 0; n < 4; ++n) B[n] = wb[(size_t)kt * 2048 + n * 64];
    };
    auto MM2 = [&](const bf16x8* B, int kt) {
        const unsigned short* ab = hf + kt * 2048 + lane * 8;
#pragma unroll
        for (int mt = 0; mt < 4; ++mt) {
            const bf16x8 a = *reinterpret_cast<const bf16x8*>(ab + mt * 512);
#pragma unroll
            for (int n = 0; n < 4; ++n) acc[mt][n] = MFMA16(a, B[n], acc[mt][n]);
        }
    };

    bf16x8 C0[4], C1[4], C2[4];
    LB2(C0, 0); LB2(C1, 1);
    for (int kt = 0; kt < 30; kt += 3) {
        LB2(C2, kt + 2); MM2(C0, kt);
        LB2(C0, kt + 3); MM2(C1, kt + 1);
        LB2(C1, kt + 4); MM2(C2, kt + 2);
    }
    MM2(C0, 30);
    MM2(C1, 31);

    __syncthreads();   // all hf reads done; reuse as ys (f32, [64][512])

    float* ys = reinterpret_cast<float*>(hf);
#pragma unroll
    for (int n = 0; n < 4; ++n) {
        const int col = w * 64 + n * 16 + lr;
        const float bvv = b2[col];
#pragma unroll
        for (int mt = 0; mt < 4; ++mt)
#pragma unroll
            for (int j = 0; j < 4; ++j)
                ys[(mt * 16 + lk * 4 + j) * 512 + col] = acc[mt][n][j] + bvv;
    }
    __syncthreads();

    // ---------------- epilogue: rotation + coalesced store ----------------
    {
        const int n = tid;          // output column 0..511
        const int p = n >> 7;
        const int f = n & 127;
        float* op = out + (size_t)row0 * 512 + n;
        if (p == 0) {
#pragma unroll 4
            for (int m = 0; m < BMA; ++m)
                if (row0 + m < nrows) op[(size_t)m * 512] = ys[m * 512 + f];
        } else {
            const int c = p - 1;
#pragma unroll 4
            for (int m = 0; m < BMA; ++m)
                if (row0 + m < nrows) {
                    const float v = R_s[m * 9 + c * 3 + 0] * ys[m * 512 + 128 + f]
                                  + R_s[m * 9 + c * 3 + 1] * ys[m * 512 + 256 + f]
                                  + R_s[m * 9 + c * 3 + 2] * ys[m * 512 + 384 + f];
                    op[(size_t)m * 512] = v;
                }
        }
    }
}

extern "C" void kernel_launch(void* const* d_in, const int* in_sizes, int n_in,
                              void* d_out, int out_size, void* d_ws, size_t ws_size,
                              hipStream_t stream) {
    const float* x     = (const float*)d_in[0];
    const float* rot   = (const float*)d_in[1];
    const float* extra = (const float*)d_in[2];
    const float* W1    = (const float*)d_in[3];
    const float* b1    = (const float*)d_in[4];
    const float* W2    = (const float*)d_in[5];
    const float* b2    = (const float*)d_in[6];
    float* out = (float*)d_out;

    const int nrows = in_sizes[0] / 512;

    // ws: W1 packed (2,359,296 B) | W2 packed (1,048,576 B) | h spill blocks
    unsigned short* w1p = (unsigned short*)d_ws;
    unsigned short* w2p = (unsigned short*)((char*)d_ws + 2359296);
    char* hspill        = (char*)d_ws + 2359296 + 1048576;
    char* hmain         = (char*)d_out;   // h block i occupies exactly y block i's bytes

    const int nblk = (nrows + BMA - 1) / BMA;
    long long out_bytes = (long long)out_size * 4;
    int spill_start = (int)(out_bytes / HBLK_BYTES);
    if (spill_start > nblk) spill_start = nblk;

    pack_w_kernel<<<(36 * 64 * 64 + 255) / 256, 256, 0, stream>>>(W1, w1p, HIDDEN, 6, 36 * 64);
    pack_w_kernel<<<(32 * 32 * 64 + 255) / 256, 256, 0, stream>>>(W2, w2p, OUT_D, 5, 32 * 32);

    gemm1_kernel<<<nblk, 512, 0, stream>>>(x, rot, extra, b1, (const bf16x8*)w1p,
                                           hmain, hspill, nrows, spill_start);
    gemm2_kernel<<<nblk, 512, 0, stream>>>(rot, b2, (const bf16x8*)w2p,
                                           hmain, hspill, out, nrows, spill_start);
}